// Round 4
// baseline (1315.721 us; speedup 1.0000x reference)
//
#include <hip/hip_runtime.h>

// B=2, H=16, L=2048, D=64. Inputs q,k,v fp32, mask int32.
// Outputs (concatenated in d_out, **fp32** this round): out (B,H,L,D) then attn (B,H,L,L).
#define L_ 2048
#define D_ 64

typedef __attribute__((ext_vector_type(8))) short bf16x8;
typedef __attribute__((ext_vector_type(4))) float f32x4;

__device__ __forceinline__ unsigned short f2bf(float x) {
  union { float f; unsigned u; } v; v.f = x;
  return (unsigned short)((v.u + 0x7fffu + ((v.u >> 16) & 1u)) >> 16);
}
__device__ __forceinline__ float bf2f(unsigned short h) {
  union { unsigned u; float f; } v; v.u = ((unsigned)h) << 16; return v.f;
}

// K fp32 -> (kh, kl) bf16 split: k = kh + kl + O(2^-18 rel)
__global__ __launch_bounds__(256) void ksplit(const float* __restrict__ k,
                                              unsigned short* __restrict__ kh,
                                              unsigned short* __restrict__ kl) {
  size_t o = ((size_t)blockIdx.x * 256 + threadIdx.x) * 8;
  #pragma unroll
  for (int j = 0; j < 8; ++j) {
    float x = k[o + j];
    unsigned short h = f2bf(x);
    kh[o + j] = h;
    kl[o + j] = f2bf(x - bf2f(h));
  }
}

// One workgroup = one (bh, 16 q-rows) tile. 256 threads = 4 waves.
template<bool USE_WS>
__global__ __launch_bounds__(256) void attn_fused(
    const float* __restrict__ qf, const float* __restrict__ kf,
    const unsigned short* __restrict__ khp, const unsigned short* __restrict__ klp,
    const int* __restrict__ mask, const float* __restrict__ vf,
    float* __restrict__ outp, float* __restrict__ attnp) {
  __shared__ float S[16][2052];            // 131328 B  raw scores -> exp values
  __shared__ unsigned short Qh[16][72];    //   2304 B  hi(q/8) bf16
  __shared__ unsigned short Ql[16][72];    //   2304 B  lo correction bf16
  __shared__ float red[16][17];
  __shared__ float rowM[16];
  __shared__ float rowL[16];
  __shared__ float Ored[4][16][64];        //  16384 B  split-K PV partials

  const int tid = threadIdx.x;
  const int wg  = blockIdx.x;
  const int bh  = wg >> 7;
  const int q0  = (wg & 127) << 4;
  const int b   = bh >> 4;

  // ---- stage Q: q/8 = qh + ql (bf16 pair) ----
  {
    int i = tid << 2;
    int r = i >> 6, d = i & 63;
    float4 u = *(const float4*)(qf + ((size_t)(bh * L_ + q0 + r)) * D_ + d);
    ushort4 ph, pl;
    float s;
    s = u.x * 0.125f; ph.x = f2bf(s); pl.x = f2bf(s - bf2f(ph.x));
    s = u.y * 0.125f; ph.y = f2bf(s); pl.y = f2bf(s - bf2f(ph.y));
    s = u.z * 0.125f; ph.z = f2bf(s); pl.z = f2bf(s - bf2f(ph.z));
    s = u.w * 0.125f; ph.w = f2bf(s); pl.w = f2bf(s - bf2f(ph.w));
    *(ushort4*)&Qh[r][d] = ph;
    *(ushort4*)&Ql[r][d] = pl;
  }
  __syncthreads();

  const int lane = tid & 63;
  const int wave = tid >> 6;
  const int c16  = lane & 15;
  const int quad = lane >> 4;

  // ---- QK^T -> S, split-bf16 precision (s = qh*kh + qh*kl + ql*kh) ----
  {
    bf16x8 a0h = *(const bf16x8*)&Qh[c16][quad * 8];
    bf16x8 a1h = *(const bf16x8*)&Qh[c16][32 + quad * 8];
    bf16x8 a0l = *(const bf16x8*)&Ql[c16][quad * 8];
    bf16x8 a1l = *(const bf16x8*)&Ql[c16][32 + quad * 8];
    #pragma unroll 2
    for (int ct = 0; ct < 32; ++ct) {
      int col = (wave << 9) + (ct << 4) + c16;
      bf16x8 b0h, b1h, b0l, b1l;
      if (USE_WS) {
        const unsigned short* hp = khp + (size_t)bh * (L_ * D_) + (size_t)col * D_ + quad * 8;
        const unsigned short* lp = klp + (size_t)bh * (L_ * D_) + (size_t)col * D_ + quad * 8;
        b0h = *(const bf16x8*)(hp);
        b1h = *(const bf16x8*)(hp + 32);
        b0l = *(const bf16x8*)(lp);
        b1l = *(const bf16x8*)(lp + 32);
      } else {
        const float* kp = kf + (size_t)bh * (L_ * D_) + (size_t)col * D_ + quad * 8;
        #pragma unroll
        for (int j = 0; j < 4; ++j) {
          float x0 = kp[j], x1 = kp[4 + j], x2 = kp[32 + j], x3 = kp[36 + j];
          b0h[j]     = (short)f2bf(x0); b0l[j]     = (short)f2bf(x0 - bf2f((unsigned short)b0h[j]));
          b0h[4 + j] = (short)f2bf(x1); b0l[4 + j] = (short)f2bf(x1 - bf2f((unsigned short)b0h[4 + j]));
          b1h[j]     = (short)f2bf(x2); b1l[j]     = (short)f2bf(x2 - bf2f((unsigned short)b1h[j]));
          b1h[4 + j] = (short)f2bf(x3); b1l[4 + j] = (short)f2bf(x3 - bf2f((unsigned short)b1h[4 + j]));
        }
      }
      f32x4 acc = {0.f, 0.f, 0.f, 0.f};
      acc = __builtin_amdgcn_mfma_f32_16x16x32_bf16(a0h, b0h, acc, 0, 0, 0);
      acc = __builtin_amdgcn_mfma_f32_16x16x32_bf16(a1h, b1h, acc, 0, 0, 0);
      acc = __builtin_amdgcn_mfma_f32_16x16x32_bf16(a0h, b0l, acc, 0, 0, 0);
      acc = __builtin_amdgcn_mfma_f32_16x16x32_bf16(a1h, b1l, acc, 0, 0, 0);
      acc = __builtin_amdgcn_mfma_f32_16x16x32_bf16(a0l, b0h, acc, 0, 0, 0);
      acc = __builtin_amdgcn_mfma_f32_16x16x32_bf16(a1l, b1h, acc, 0, 0, 0);
      int r0 = quad << 2;                      // D: col=lane&15, row=quad*4+reg
      S[r0 + 0][col] = acc[0];
      S[r0 + 1][col] = acc[1];
      S[r0 + 2][col] = acc[2];
      S[r0 + 3][col] = acc[3];
    }
  }
  __syncthreads();

  const int row = tid >> 4;
  const int sub = tid & 15;

  // ---- row max (softmax shift-invariance: mask not needed here) ----
  {
    float m = -1e30f;
    for (int t = 0; t < 32; ++t) {
      const float4 s4 = *(const float4*)&S[row][(sub + (t << 4)) << 2];
      m = fmaxf(m, fmaxf(fmaxf(s4.x, s4.y), fmaxf(s4.z, s4.w)));
    }
    red[row][sub] = m;
  }
  __syncthreads();
  if (sub == 0) {
    float m = -1e30f;
    for (int i = 0; i < 16; ++i) m = fmaxf(m, red[row][i]);
    rowM[row] = m;
  }
  __syncthreads();

  // ---- e = mask ? exp(s-m) : 0 ; write back; partial sums ----
  {
    const float m = rowM[row];
    const int* mrow = mask + ((size_t)(b * L_ + q0 + row)) * L_;
    float l = 0.f;
    for (int t = 0; t < 32; ++t) {
      int c = (sub + (t << 4)) << 2;
      float4 s4 = *(const float4*)&S[row][c];
      int4 mk = *(const int4*)(mrow + c);
      s4.x = mk.x ? __expf(s4.x - m) : 0.f;
      s4.y = mk.y ? __expf(s4.y - m) : 0.f;
      s4.z = mk.z ? __expf(s4.z - m) : 0.f;
      s4.w = mk.w ? __expf(s4.w - m) : 0.f;
      *(float4*)&S[row][c] = s4;
      l += (s4.x + s4.y) + (s4.z + s4.w);
    }
    red[row][sub] = l;
  }
  __syncthreads();
  if (sub == 0) {
    float l = 0.f;
    for (int i = 0; i < 16; ++i) l += red[row][i];
    rowL[row] = (l > 0.f) ? (1.f / l) : 0.f;
  }
  __syncthreads();

  // ---- attn = e * inv -> fp32 stores (coalesced; drain during PV) ----
  {
    float* ab = attnp + ((size_t)(bh * L_ + q0)) * L_;
    for (int it = 0; it < 32; ++it) {
      int idx = (it << 10) + (tid << 2);
      int r = idx >> 11, c = idx & 2047;
      float inv = rowL[r];
      float4 e4 = *(const float4*)&S[r][c];
      float4 p;
      p.x = e4.x * inv; p.y = e4.y * inv; p.z = e4.z * inv; p.w = e4.w * inv;
      *(float4*)(ab + (size_t)r * L_ + c) = p;
    }
  }

  // ---- PV: O = P*V, split-K across waves; V read fp32 direct (L2-resident) ----
  {
    const float inv = rowL[c16];
    const float* vb = vf + (size_t)bh * (L_ * D_);
    f32x4 o0 = {0.f,0.f,0.f,0.f}, o1 = o0, o2 = o0, o3 = o0;
    for (int kt = 0; kt < 16; ++kt) {
      int k0 = ((wave << 4) + kt) << 5;
      const float* sp = &S[c16][k0 + quad * 8];
      float4 ea = *(const float4*)sp;
      float4 eb = *(const float4*)(sp + 4);
      bf16x8 af;
      af[0] = (short)f2bf(ea.x * inv); af[1] = (short)f2bf(ea.y * inv);
      af[2] = (short)f2bf(ea.z * inv); af[3] = (short)f2bf(ea.w * inv);
      af[4] = (short)f2bf(eb.x * inv); af[5] = (short)f2bf(eb.y * inv);
      af[6] = (short)f2bf(eb.z * inv); af[7] = (short)f2bf(eb.w * inv);
      const float* vp = vb + (size_t)(k0 + quad * 8) * D_ + c16;
      bf16x8 b0, b1, b2, b3;
      #pragma unroll
      for (int j = 0; j < 8; ++j) {
        const float* vr = vp + (size_t)j * D_;
        b0[j] = (short)f2bf(vr[0]);
        b1[j] = (short)f2bf(vr[16]);
        b2[j] = (short)f2bf(vr[32]);
        b3[j] = (short)f2bf(vr[48]);
      }
      o0 = __builtin_amdgcn_mfma_f32_16x16x32_bf16(af, b0, o0, 0, 0, 0);
      o1 = __builtin_amdgcn_mfma_f32_16x16x32_bf16(af, b1, o1, 0, 0, 0);
      o2 = __builtin_amdgcn_mfma_f32_16x16x32_bf16(af, b2, o2, 0, 0, 0);
      o3 = __builtin_amdgcn_mfma_f32_16x16x32_bf16(af, b3, o3, 0, 0, 0);
    }
    int r0 = quad << 2;
    #pragma unroll
    for (int g = 0; g < 4; ++g) {
      Ored[wave][r0 + g][c16]      = o0[g];
      Ored[wave][r0 + g][16 + c16] = o1[g];
      Ored[wave][r0 + g][32 + c16] = o2[g];
      Ored[wave][r0 + g][48 + c16] = o3[g];
    }
  }
  __syncthreads();
  {
    int r = tid >> 4, d0 = (tid & 15) << 2;
    float4 s = {0.f, 0.f, 0.f, 0.f};
    #pragma unroll
    for (int w = 0; w < 4; ++w) {
      s.x += Ored[w][r][d0 + 0];
      s.y += Ored[w][r][d0 + 1];
      s.z += Ored[w][r][d0 + 2];
      s.w += Ored[w][r][d0 + 3];
    }
    *(float4*)(outp + ((size_t)(bh * L_ + q0 + r)) * D_ + d0) = s;
  }
}

extern "C" void kernel_launch(void* const* d_in, const int* in_sizes, int n_in,
                              void* d_out, int out_size, void* d_ws, size_t ws_size,
                              hipStream_t stream) {
  const float* q = (const float*)d_in[0];
  const float* k = (const float*)d_in[1];
  const float* v = (const float*)d_in[2];
  const int* mask = (const int*)d_in[3];
  float* outp  = (float*)d_out;                      // out: 4194304 f32
  float* attnp = outp + (size_t)4194304;             // attn: 134217728 f32

  if (ws_size >= (size_t)16777216) {                 // kh + kl, 8 MB each
    unsigned short* kh = (unsigned short*)d_ws;
    unsigned short* kl = kh + (size_t)4194304;
    ksplit<<<2048, 256, 0, stream>>>(k, kh, kl);
    attn_fused<true><<<4096, 256, 0, stream>>>(q, k, kh, kl, mask, v, outp, attnp);
  } else {
    attn_fused<false><<<4096, 256, 0, stream>>>(q, k, nullptr, nullptr, mask, v, outp, attnp);
  }
}